// Round 8
// baseline (253.195 us; speedup 1.0000x reference)
//
#include <hip/hip_runtime.h>

// Shapes (fixed): B=64 H=16 T=4 Dk=128 Dv=256
#define BH 1024
#define TT 4
#define DK 128
#define DV 256
#define NW 4          // waves per block
#define RPW 32        // rows per wave = DK/NW
#define CH 128        // cols per block (2 halves per bh)
#define NBLK 512      // persistent blocks
#define NU 4          // units (bh-halves) per block

// R8 = R7 resubmitted (R7 failed on infra, kernel never ran).
// Persistent software-pipelined blocks (copy-shaped memory stream).
// R6 post-mortem: 4 structurally different one-shot kernels all pin at
// ~2.5 TB/s while fillBuffer hits 6.77 TB/s in the same run -> the cap is
// the one-shot read-burst/lull/write-burst lifecycle, not the HW. Here each
// block processes 4 units; pass 2 interleaves {store updated row of unit u,
// load same row of unit u+1} per 512B row-pair, giving every wave a
// continuous mixed R/W stream like a copy kernel. Next unit's k/q/v/g/beta
// prefetch during pass 2. Math per unit = R6's closed-form unroll:
//   c_t=S0^T k_t, p_t=S0^T q_t, A=k_s.k_t, B=k_s.q_t, triangular solve for
//   d_t, S4 = G3 S0 + sum_t M[t][3] k_t (x) d_t, o_t = G_t p_t + sum B d_s.
__global__ __launch_bounds__(256)
void delta_rule_kernel(const float* __restrict__ q,
                       const float* __restrict__ k,
                       const float* __restrict__ v,
                       const float* __restrict__ g,
                       const float* __restrict__ beta,
                       const float* __restrict__ s0,
                       float* __restrict__ out)
{
    const int b    = blockIdx.x;
    const int half = b & 1;                // same for all 4 units (stride 512)
    const int tid  = threadIdx.x;
    const int w    = tid >> 6;             // wave 0..3, rows [32w,32w+32)
    const int l    = tid & 63;             // lane, 2 cols
    const int col  = half * CH + (l << 1); // loop-invariant across units
    const int lc   = l << 1;
    const int r0   = w * RPW;
    const int e0   = tid, e1 = tid + 256;  // element = t*128 + row

    __shared__ __align__(16) float ksh[2][DK][4];    // [buf][row][t]
    __shared__ __align__(16) float qsh[2][DK][4];
    __shared__ __align__(16) float redc[TT][NW][CH]; // c-partial exchange
    __shared__ __align__(16) float redp[TT][NW][CH]; // p-partial exchange

    // ---- prologue: unit 0 loads (staging first -> retires first) ----
    int bh = b >> 1;
    {
        const float* kb = k + (size_t)bh * TT * DK;
        const float* qb = q + (size_t)bh * TT * DK;
        const float kl0 = kb[e0], kl1 = kb[e1];
        const float ql0 = qb[e0], ql1 = qb[e1];
        ksh[0][e0 & 127][e0 >> 7] = kl0;
        ksh[0][e1 & 127][e1 >> 7] = kl1;
        qsh[0][e0 & 127][e0 >> 7] = ql0;
        qsh[0][e1 & 127][e1 >> 7] = ql1;
    }
    float4 gq = *(const float4*)(g    + (size_t)bh * TT);
    float4 bq = *(const float4*)(beta + (size_t)bh * TT);
    float2 va[TT];
    {
        const float* vb = v + (size_t)bh * TT * DV;
#pragma unroll
        for (int t = 0; t < TT; ++t)
            va[t] = *(const float2*)&vb[t * DV + col];
    }
    float2 s2[RPW];
    {
        const float* sp = s0 + (size_t)bh * DK * DV;
#pragma unroll
        for (int i = 0; i < RPW; ++i)
            s2[i] = *(const float2*)&sp[(size_t)(r0 + i) * DV + col];
    }
    __syncthreads();   // B0: ksh[0]/qsh[0] visible

#pragma unroll
    for (int u = 0; u < NU; ++u) {
        const int par = u & 1;
        const int bhu = (b >> 1) + (u << 8);     // (b + u*512) >> 1
        const int bhn = bhu + 256;               // next unit's bh
        float* __restrict__ out_p  = out + (size_t)bhu * TT * DV;
        float* __restrict__ sout_p = out + (size_t)BH * TT * DV + (size_t)bhu * DK * DV;

        // ---- decay products ----
        const float y0 = expf(gq.x), y1 = expf(gq.y), y2 = expf(gq.z), y3 = expf(gq.w);
        const float G0 = y0, G1 = y0*y1, G2 = y0*y1*y2, G3 = y0*y1*y2*y3;
        const float M01 = y1, M02 = y1*y2, M03 = y1*y2*y3;
        const float M12 = y2, M13 = y2*y3, M23 = y3;
        const float E = G3;
        const float bt0 = bq.x, bt1 = bq.y, bt2 = bq.z, bt3 = bq.w;

        // ---- Gram scalars (wave-redundant butterfly) ----
        const float4 kA = *(const float4*)&ksh[par][l][0];
        const float4 kB = *(const float4*)&ksh[par][l + 64][0];
        const float4 qA = *(const float4*)&qsh[par][l][0];
        const float4 qB = *(const float4*)&qsh[par][l + 64][0];
        const float a0[4] = {kA.x, kA.y, kA.z, kA.w};
        const float a1[4] = {kB.x, kB.y, kB.z, kB.w};
        const float b0[4] = {qA.x, qA.y, qA.z, qA.w};
        const float b1[4] = {qB.x, qB.y, qB.z, qB.w};
        float AA[4][4], BBm[4][4];
#pragma unroll
        for (int s = 0; s < 4; ++s) {
#pragma unroll
            for (int t = 0; t < 4; ++t) {
                if (t > s) {
                    float x = fmaf(a1[s], a1[t], a0[s] * a0[t]);
#pragma unroll
                    for (int m = 1; m < 64; m <<= 1) x += __shfl_xor(x, m);
                    AA[s][t] = x;
                }
                if (t >= s) {
                    float x = fmaf(a1[s], b1[t], a0[s] * b0[t]);
#pragma unroll
                    for (int m = 1; m < 64; m <<= 1) x += __shfl_xor(x, m);
                    BBm[s][t] = x;
                }
            }
        }

        // ---- pass 1: c_t partials over this wave's 32 rows ----
        float2 c[TT] = {{0.f,0.f},{0.f,0.f},{0.f,0.f},{0.f,0.f}};
#pragma unroll
        for (int i = 0; i < RPW; ++i) {
            const float4 k4 = *(const float4*)&ksh[par][r0 + i][0]; // broadcast
            c[0].x = fmaf(s2[i].x, k4.x, c[0].x); c[0].y = fmaf(s2[i].y, k4.x, c[0].y);
            c[1].x = fmaf(s2[i].x, k4.y, c[1].x); c[1].y = fmaf(s2[i].y, k4.y, c[1].y);
            c[2].x = fmaf(s2[i].x, k4.z, c[2].x); c[2].y = fmaf(s2[i].y, k4.z, c[2].y);
            c[3].x = fmaf(s2[i].x, k4.w, c[3].x); c[3].y = fmaf(s2[i].y, k4.w, c[3].y);
        }
#pragma unroll
        for (int t = 0; t < TT; ++t)
            *(float2*)&redc[t][w][lc] = c[t];
        __syncthreads();                          // B1: c partials visible
#pragma unroll
        for (int t = 0; t < TT; ++t) {
            const float2 u0 = *(const float2*)&redc[t][0][lc];
            const float2 u1 = *(const float2*)&redc[t][1][lc];
            const float2 u2 = *(const float2*)&redc[t][2][lc];
            const float2 u3 = *(const float2*)&redc[t][3][lc];
            c[t].x = (u0.x + u1.x) + (u2.x + u3.x);
            c[t].y = (u0.y + u1.y) + (u2.y + u3.y);
        }

        // ---- triangular solve for d_t ----
        float2 d0, d1, d2, d3;
        d0.x = bt0 * (va[0].x - G0 * c[0].x);
        d0.y = bt0 * (va[0].y - G0 * c[0].y);
        d1.x = bt1 * (va[1].x - G1 * c[1].x - M01 * AA[0][1] * d0.x);
        d1.y = bt1 * (va[1].y - G1 * c[1].y - M01 * AA[0][1] * d0.y);
        d2.x = bt2 * (va[2].x - G2 * c[2].x - M02 * AA[0][2] * d0.x - M12 * AA[1][2] * d1.x);
        d2.y = bt2 * (va[2].y - G2 * c[2].y - M02 * AA[0][2] * d0.y - M12 * AA[1][2] * d1.y);
        d3.x = bt3 * (va[3].x - G3 * c[3].x - M03 * AA[0][3] * d0.x - M13 * AA[1][3] * d1.x - M23 * AA[2][3] * d2.x);
        d3.y = bt3 * (va[3].y - G3 * c[3].y - M03 * AA[0][3] * d0.y - M13 * AA[1][3] * d1.y - M23 * AA[2][3] * d2.y);

        // ---- prefetch next unit's small inputs (issue before row loop) ----
        float nkl0, nkl1, nql0, nql1;
        float4 ngq, nbq;
        float2 nva[TT];
        if (u < NU - 1) {
            const float* kbn = k + (size_t)bhn * TT * DK;
            const float* qbn = q + (size_t)bhn * TT * DK;
            nkl0 = kbn[e0]; nkl1 = kbn[e1];
            nql0 = qbn[e0]; nql1 = qbn[e1];
            ngq = *(const float4*)(g    + (size_t)bhn * TT);
            nbq = *(const float4*)(beta + (size_t)bhn * TT);
            const float* vbn = v + (size_t)bhn * TT * DV;
#pragma unroll
            for (int t = 0; t < TT; ++t)
                nva[t] = *(const float2*)&vbn[t * DV + col];
        }

        // ---- pass 2: p partials + fused update + store, interleaved with
        //      next unit's state loads (the copy-shaped R/W stream) ----
        const float W0t = M03, W1t = M13, W2t = M23;   // W3 = 1
        const float* __restrict__ spn = s0 + (size_t)bhn * DK * DV;
        float2 p[TT] = {{0.f,0.f},{0.f,0.f},{0.f,0.f},{0.f,0.f}};
#pragma unroll
        for (int i = 0; i < RPW; ++i) {
            const int r = r0 + i;
            const float4 k4 = *(const float4*)&ksh[par][r][0];  // broadcast
            const float4 q4 = *(const float4*)&qsh[par][r][0];  // broadcast
            const float2 s = s2[i];
            p[0].x = fmaf(s.x, q4.x, p[0].x); p[0].y = fmaf(s.y, q4.x, p[0].y);
            p[1].x = fmaf(s.x, q4.y, p[1].x); p[1].y = fmaf(s.y, q4.y, p[1].y);
            p[2].x = fmaf(s.x, q4.z, p[2].x); p[2].y = fmaf(s.y, q4.z, p[2].y);
            p[3].x = fmaf(s.x, q4.w, p[3].x); p[3].y = fmaf(s.y, q4.w, p[3].y);
            const float h0 = W0t * k4.x, h1 = W1t * k4.y, h2 = W2t * k4.z, h3 = k4.w;
            float nx = s.x * E, ny = s.y * E;
            nx = fmaf(h0, d0.x, nx); ny = fmaf(h0, d0.y, ny);
            nx = fmaf(h1, d1.x, nx); ny = fmaf(h1, d1.y, ny);
            nx = fmaf(h2, d2.x, nx); ny = fmaf(h2, d2.y, ny);
            nx = fmaf(h3, d3.x, nx); ny = fmaf(h3, d3.y, ny);
            *(float2*)&sout_p[(size_t)r * DV + col] = make_float2(nx, ny);
            if (u < NU - 1)   // load next unit's same row into the freed regs
                s2[i] = *(const float2*)&spn[(size_t)r * DV + col];
        }
#pragma unroll
        for (int t = 0; t < TT; ++t)
            *(float2*)&redp[t][w][lc] = p[t];
        __syncthreads();                          // B2: p partials visible

        // ---- stage next unit's k/q into the other LDS buffer ----
        if (u < NU - 1) {
            ksh[par ^ 1][e0 & 127][e0 >> 7] = nkl0;
            ksh[par ^ 1][e1 & 127][e1 >> 7] = nkl1;
            qsh[par ^ 1][e0 & 127][e0 >> 7] = nql0;
            qsh[par ^ 1][e1 & 127][e1 >> 7] = nql1;
        }

        // ---- o_t: wave w owns row t=w of out ----
        {
            const float2 darr[4] = {d0, d1, d2, d3};
            const float Gt[4] = {G0, G1, G2, G3};
            const float Mm[4][4] = {{1.f, M01, M02, M03},
                                    {0.f, 1.f, M12, M13},
                                    {0.f, 0.f, 1.f, M23},
                                    {0.f, 0.f, 0.f, 1.f}};
            const int t = w;
            const float2 u0 = *(const float2*)&redp[t][0][lc];
            const float2 u1 = *(const float2*)&redp[t][1][lc];
            const float2 u2 = *(const float2*)&redp[t][2][lc];
            const float2 u3 = *(const float2*)&redp[t][3][lc];
            float ox = Gt[t] * ((u0.x + u1.x) + (u2.x + u3.x));
            float oy = Gt[t] * ((u0.y + u1.y) + (u2.y + u3.y));
#pragma unroll
            for (int s = 0; s < TT; ++s) {
                if (s <= t) {
                    const float cf = Mm[s][t] * BBm[s][t];
                    ox = fmaf(cf, darr[s].x, ox);
                    oy = fmaf(cf, darr[s].y, oy);
                }
            }
            *(float2*)&out_p[t * DV + col] = make_float2(ox, oy);
        }

        if (u < NU - 1) {
            __syncthreads();                      // B3: ksh_next visible;
            gq = ngq; bq = nbq;                   //     redp/redc safe to reuse
#pragma unroll
            for (int t = 0; t < TT; ++t) va[t] = nva[t];
        }
    }
}

extern "C" void kernel_launch(void* const* d_in, const int* in_sizes, int n_in,
                              void* d_out, int out_size, void* d_ws, size_t ws_size,
                              hipStream_t stream) {
    const float* q    = (const float*)d_in[0];
    const float* k    = (const float*)d_in[1];
    const float* v    = (const float*)d_in[2];
    const float* g    = (const float*)d_in[3];
    const float* beta = (const float*)d_in[4];
    const float* s0   = (const float*)d_in[5];
    float* out = (float*)d_out;

    delta_rule_kernel<<<dim3(NBLK), dim3(256), 0, stream>>>(q, k, v, g, beta, s0, out);
}